// Round 4
// baseline (1370.390 us; speedup 1.0000x reference)
//
#include <hip/hip_runtime.h>

#define D 256
typedef unsigned short u16;
using short8  = __attribute__((ext_vector_type(8))) short;
using ushort8 = __attribute__((ext_vector_type(8))) unsigned short;
using f32x4   = __attribute__((ext_vector_type(4))) float;

#define BCHUNK  4096     // edges per binning block
#define FBINCAP 17500    // per fine-bin capacity (avg 16384, ~8.7 sigma margin)

__device__ __forceinline__ u16 f2bf(float f) {
    unsigned u = __float_as_uint(f);
    unsigned r = (u + 0x7FFFu + ((u >> 16) & 1u)) >> 16;
    return (u16)r;
}
__device__ __forceinline__ float bf2f(u16 v) {
    return __uint_as_float(((unsigned)v) << 16);
}

__device__ __forceinline__ void load_lds16(const u16* g, u16* l) {
    __builtin_amdgcn_global_load_lds(
        (const __attribute__((address_space(1))) void*)g,
        (__attribute__((address_space(3))) void*)l, 16, 0, 0);
}

// ---------------- CSR build ----------------

__global__ void k_initcur(int* __restrict__ bincur, int nfbin) {
    int i = threadIdx.x;
    if (i < nfbin) bincur[i] = i * FBINCAP;
}

__global__ __launch_bounds__(256)
void k_binf(const int* __restrict__ src, const int* __restrict__ dst,
            int* __restrict__ bincur, unsigned* __restrict__ bins,
            int E, int nfbin) {
    __shared__ int cnt[256];
    __shared__ int bpos[256];
    int t = threadIdx.x;
    int base = blockIdx.x * BCHUNK;
    cnt[t] = 0;
    __syncthreads();
    int lim = E - base; if (lim > BCHUNK) lim = BCHUNK;
    for (int i = t; i < lim; i += 256)
        atomicAdd(&cnt[dst[base + i] >> 9], 1);
    __syncthreads();
    if (t < nfbin) {
        int c = cnt[t];
        bpos[t] = c > 0 ? atomicAdd(&bincur[t], c) : 0;
    }
    __syncthreads();
    cnt[t] = 0;
    __syncthreads();
    for (int i = t; i < lim; i += 256) {
        int d = dst[base + i], s = src[base + i];
        int fb = d >> 9;
        int r = atomicAdd(&cnt[fb], 1);
        bins[(size_t)bpos[fb] + r] = (unsigned)s | ((unsigned)(d & 511) << 17);
    }
}

// One block per fine bin: LDS hist(512) -> scan -> placement -> PER-DST SORT
// (ascending src) -> coalesced srcs write. Sorting makes every agg wave walk
// src space monotonically; with all waves co-resident the chip-wide src
// working set becomes a moving ~10MB window instead of the full 25.6MB ->
// higher L2 hit rate on the gather.
__global__ __launch_bounds__(256)
void k_csrf(const unsigned* __restrict__ bins, const int* __restrict__ bincur,
            int* __restrict__ offs, int* __restrict__ ends,
            int* __restrict__ srcs, int N) {
    __shared__ int cnt[512];
    __shared__ int cur[512];
    __shared__ int ssum[256];
    __shared__ int loc[FBINCAP];
    int b = blockIdx.x, t = threadIdx.x;
    int bbase = b * FBINCAP;
    int ecnt = bincur[b] - bbase;
    cnt[t] = 0; cnt[t + 256] = 0;
    __syncthreads();
    const unsigned* bp = bins + bbase;
    for (int i = t; i < ecnt; i += 256)
        atomicAdd(&cnt[bp[i] >> 17], 1);
    __syncthreads();
    int a0 = cnt[2 * t], a1 = cnt[2 * t + 1];
    ssum[t] = a0 + a1;
    __syncthreads();
    for (int o = 1; o < 256; o <<= 1) {
        int x = (t >= o) ? ssum[t - o] : 0;
        __syncthreads();
        ssum[t] += x;
        __syncthreads();
    }
    int excl = ssum[t] - (a0 + a1);
    cur[2 * t] = excl;
    cur[2 * t + 1] = excl + a0;
    int nbase = b << 9;
    int l0 = nbase + 2 * t, l1 = l0 + 1;
    if (l0 < N) { offs[l0] = bbase + excl;      ends[l0] = bbase + excl + a0; }
    if (l1 < N) { offs[l1] = bbase + excl + a0; ends[l1] = bbase + excl + a0 + a1; }
    __syncthreads();
    for (int i = t; i < ecnt; i += 256) {
        unsigned v = bp[i];
        int p = atomicAdd(&cur[v >> 17], 1);
        loc[p] = (int)(v & 0x1FFFFu);
    }
    __syncthreads();
    // per-dst insertion sort (lists avg ~32; values are src ids).
    // after placement cur[d] = segment end; cnt[d] = segment length.
    for (int d = t; d < 512; d += 256) {
        int len = cnt[d];
        int st  = cur[d] - len;
        for (int i = 1; i < len; i++) {
            int v = loc[st + i];
            int j = i - 1;
            while (j >= 0 && loc[st + j] > v) {
                loc[st + j + 1] = loc[st + j];
                j--;
            }
            loc[st + j + 1] = v;
        }
    }
    __syncthreads();
    for (int i = t; i < ecnt; i += 256)
        srcs[bbase + i] = loc[i];
}

// ---------------- embedding gather -> bf16 ----------------

__global__ void k_gather_bf(const int* __restrict__ x, const float* __restrict__ emb,
                            u16* __restrict__ h, int N) {
    int idx = blockIdx.x * blockDim.x + threadIdx.x;
    if (idx >= N * 64) return;
    int node = idx >> 6, c = idx & 63;
    int s = x[node];
    float4 v = ((const float4*)emb)[(size_t)s * 64 + c];
    ushort4 o;
    o.x = f2bf(v.x); o.y = f2bf(v.y); o.z = f2bf(v.z); o.w = f2bf(v.w);
    ((ushort4*)h)[(size_t)node * 64 + c] = o;
}

// ---------------- weight fp32 -> bf16 ----------------

__global__ void k_cvtw(const float* w0, const float* w1, const float* w2,
                       const float* w3, const float* w4, const float* w5,
                       const float* w6, u16* __restrict__ out) {
    int idx = blockIdx.x * blockDim.x + threadIdx.x;
    if (idx >= 7 * 65536) return;
    int m = idx >> 16, off = idx & 65535;
    const float* w = w0;
    if (m == 1) w = w1; else if (m == 2) w = w2; else if (m == 3) w = w3;
    else if (m == 4) w = w4; else if (m == 5) w = w5; else if (m == 6) w = w6;
    out[idx] = f2bf(w[off]);
}

// ---------------- mean aggregation, 128-col half ----------------
// 256B per edge per pass = the fetch-granule optimum (R3: 128B quarters
// refetch ~256B anyway; R2: 512B full rows double the per-pass WS).

__global__ __launch_bounds__(256)
void k_agg_h(const u16* __restrict__ h, const int* __restrict__ offs,
             const int* __restrict__ ends, const int* __restrict__ srcs,
             u16* __restrict__ out, int colOff, int N) {
    int wid = (blockIdx.x * blockDim.x + threadIdx.x) >> 6;
    int lane = threadIdx.x & 63;
    if (wid >= N) return;
    int beg = offs[wid], end = ends[wid];
    int q = lane >> 4;             // edge slot 0..3
    int cl = lane & 15;            // 16B chunk within the 256B half-row
    const u16* hb = h + colOff + cl * 8;
    float acc[8];
    #pragma unroll
    for (int i = 0; i < 8; i++) acc[i] = 0.f;
    int e = beg + q;
    for (; e + 12 < end; e += 16) {
        int j0 = srcs[e], j1 = srcs[e + 4], j2 = srcs[e + 8], j3 = srcs[e + 12];
        ushort8 v0 = *(const ushort8*)&hb[(size_t)j0 * D];
        ushort8 v1 = *(const ushort8*)&hb[(size_t)j1 * D];
        ushort8 v2 = *(const ushort8*)&hb[(size_t)j2 * D];
        ushort8 v3 = *(const ushort8*)&hb[(size_t)j3 * D];
        #pragma unroll
        for (int i = 0; i < 8; i++)
            acc[i] += (bf2f(v0[i]) + bf2f(v1[i])) + (bf2f(v2[i]) + bf2f(v3[i]));
    }
    for (; e < end; e += 4) {
        int j = srcs[e];
        ushort8 v = *(const ushort8*)&hb[(size_t)j * D];
        #pragma unroll
        for (int i = 0; i < 8; i++) acc[i] += bf2f(v[i]);
    }
    #pragma unroll
    for (int i = 0; i < 8; i++) {
        acc[i] += __shfl_xor(acc[i], 16);
        acc[i] += __shfl_xor(acc[i], 32);
    }
    if (q == 0) {
        int dg = end - beg;
        float inv = 1.0f / (float)(dg < 1 ? 1 : dg);
        ushort8 o;
        #pragma unroll
        for (int i = 0; i < 8; i++) o[i] = f2bf(acc[i] * inv);
        *(ushort8*)&out[(size_t)wid * D + colOff + cl * 8] = o;
    }
}

// ---------------- fused MFMA GEMM: triple-buffer BK=32, counted vmcnt ----------------
// (unchanged from R3 — correct; attribution pending a round where it
// surfaces in top-5)

__global__ __launch_bounds__(512, 4)
void k_fgemm(const u16* __restrict__ A0, const u16* __restrict__ W0,
             const u16* __restrict__ A1, const u16* __restrict__ W1,
             int npairs,
             const float* __restrict__ bias, const float* __restrict__ prelu_a,
             void* __restrict__ outp, int out_bf16, int M) {
    __shared__ u16 As[3][128 * 32];   // 8KB each
    __shared__ u16 Bs[3][256 * 32];   // 16KB each
    int t = threadIdx.x;
    int wave = t >> 6, lane = t & 63;
    int r = lane & 15, quad = lane >> 4;
    int wm = (wave & 1) * 64;
    int wn = (wave >> 1) * 64;
    int m0 = blockIdx.x * 128;

    f32x4 acc[4][4];
    #pragma unroll
    for (int i = 0; i < 4; i++)
        #pragma unroll
        for (int j = 0; j < 4; j++)
            acc[i][j] = (f32x4){0.f, 0.f, 0.f, 0.f};

    // staging: per wave-load, 64 lanes x 16B = 16 rows x 64B (4 chunks/row).
    int arow = wave * 16 + (lane >> 2);          // A row for this lane's 16B
    int scol = (((lane & 3) ^ ((lane >> 3) & 3)) << 3);  // pre-swizzled src col (u16)
    int nkt = npairs * 8;                        // K-steps of 32

    auto STAGE = [&](int buf, int kt) {
        const u16* Ag = (kt >= 8) ? A1 : A0;
        const u16* Wg = (kt >= 8) ? W1 : W0;
        int k0 = (kt & 7) * 32;
        load_lds16(Ag + (size_t)(m0 + arow) * D + k0 + scol,
                   &As[buf][wave * 512]);
        #pragma unroll
        for (int l = 0; l < 2; l++)
            load_lds16(Wg + (size_t)(l * 128 + arow) * D + k0 + scol,
                       &Bs[buf][l * 4096 + wave * 512]);
    };

    STAGE(0, 0);
    if (nkt > 1) STAGE(1, 1);

    int pch = quad ^ ((r >> 1) & 3);   // swizzled chunk for fragment reads
    int b0 = 0, b2 = 2;                // buf of step kt, buf to stage (kt+2)
    for (int kt = 0; kt < nkt; ++kt) {
        if (kt + 1 < nkt) asm volatile("s_waitcnt vmcnt(3)" ::: "memory");
        else              asm volatile("s_waitcnt vmcnt(0)" ::: "memory");
        __builtin_amdgcn_s_barrier();
        asm volatile("" ::: "memory");

        if (kt + 2 < nkt) STAGE(b2, kt + 2);

        short8 a[4], b[4];
        #pragma unroll
        for (int mt = 0; mt < 4; mt++)
            a[mt] = *(const short8*)&As[b0][(wm + mt * 16 + r) * 32 + pch * 8];
        #pragma unroll
        for (int nt = 0; nt < 4; nt++)
            b[nt] = *(const short8*)&Bs[b0][(wn + nt * 16 + r) * 32 + pch * 8];

        __builtin_amdgcn_s_setprio(1);
        #pragma unroll
        for (int mt = 0; mt < 4; mt++)
            #pragma unroll
            for (int nt = 0; nt < 4; nt++)
                acc[mt][nt] = __builtin_amdgcn_mfma_f32_16x16x32_bf16(
                    a[mt], b[nt], acc[mt][nt], 0, 0, 0);
        __builtin_amdgcn_s_setprio(0);

        b0 = (b0 == 2) ? 0 : b0 + 1;
        b2 = (b2 == 2) ? 0 : b2 + 1;
    }

    float pa = prelu_a ? *prelu_a : 0.f;
    int dop = prelu_a != nullptr;
    #pragma unroll
    for (int nt = 0; nt < 4; nt++) {
        int col = wn + nt * 16 + r;
        float bv = bias ? bias[col] : 0.f;
        #pragma unroll
        for (int mt = 0; mt < 4; mt++) {
            #pragma unroll
            for (int i = 0; i < 4; i++) {
                int row = m0 + wm + mt * 16 + quad * 4 + i;
                if (row < M) {
                    float v = acc[mt][nt][i] + bv;
                    if (dop) v = (v >= 0.f) ? v : pa * v;
                    if (out_bf16)
                        ((u16*)outp)[(size_t)row * D + col] = f2bf(v);
                    else
                        ((float*)outp)[(size_t)row * D + col] = v;
                }
            }
        }
    }
}

// ---------------- launcher ----------------

extern "C" void kernel_launch(void* const* d_in, const int* in_sizes, int n_in,
                              void* d_out, int out_size, void* d_ws, size_t ws_size,
                              hipStream_t stream) {
    const int*   x    = (const int*)d_in[0];
    const int*   ei   = (const int*)d_in[1];
    const float* emb  = (const float*)d_in[3];
    const float* Wl[3] = {(const float*)d_in[4],  (const float*)d_in[8],  (const float*)d_in[12]};
    const float* bl[3] = {(const float*)d_in[5],  (const float*)d_in[9],  (const float*)d_in[13]};
    const float* Wr[3] = {(const float*)d_in[6],  (const float*)d_in[10], (const float*)d_in[14]};
    const float* pa[3] = {(const float*)d_in[7],  (const float*)d_in[11], (const float*)d_in[15]};
    const float* Wout = (const float*)d_in[16];
    const float* bout = (const float*)d_in[17];

    int N = in_sizes[0];
    int E = in_sizes[1] / 2;
    const int* src = ei;
    const int* dst = ei + E;
    int nfbin = (N + 511) >> 9;    // 196 for N=100000

    char* ws = (char*)d_ws;
    size_t off = 0;
    auto walloc = [&](size_t bytes) -> void* {
        void* p = ws + off;
        off += (bytes + 255) & ~(size_t)255;
        return p;
    };
    // tile staging over-reads up to ~49 KB past row M-1: keep activations mid-ws
    u16* hA   = (u16*)walloc((size_t)N * D * sizeof(u16));
    u16* hB   = (u16*)walloc((size_t)N * D * sizeof(u16));
    u16* mean = (u16*)walloc((size_t)N * D * sizeof(u16));
    u16* wbf  = (u16*)walloc((size_t)7 * 65536 * sizeof(u16));
    int* offs   = (int*)walloc((size_t)N * sizeof(int));
    int* ends   = (int*)walloc((size_t)N * sizeof(int));
    int* bincur = (int*)walloc(1024);
    unsigned* bins = (unsigned*)walloc((size_t)nfbin * FBINCAP * sizeof(unsigned));
    int* srcs   = (int*)walloc((size_t)nfbin * FBINCAP * sizeof(int));

    u16* Wlb[3] = {wbf + 0 * 65536, wbf + 2 * 65536, wbf + 4 * 65536};
    u16* Wrb[3] = {wbf + 1 * 65536, wbf + 3 * 65536, wbf + 5 * 65536};
    u16* Woutb  = wbf + 6 * 65536;

    // --- weights -> bf16 ---
    k_cvtw<<<(7 * 65536 + 255) / 256, 256, 0, stream>>>(
        Wl[0], Wr[0], Wl[1], Wr[1], Wl[2], Wr[2], Wout, wbf);

    // --- CSR build: fine-bin + in-LDS sort (now src-sorted per dst) ---
    k_initcur<<<1, 256, 0, stream>>>(bincur, nfbin);
    int bb = (E + BCHUNK - 1) / BCHUNK;
    k_binf<<<bb, 256, 0, stream>>>(src, dst, bincur, bins, E, nfbin);
    k_csrf<<<nfbin, 256, 0, stream>>>(bins, bincur, offs, ends, srcs, N);

    // --- h0 = bf16(emb[x]) ---
    k_gather_bf<<<(N * 64 + 255) / 256, 256, 0, stream>>>(x, emb, hA, N);

    int mb   = (N + 127) / 128;
    int aggb = (N * 64 + 255) / 256;   // one wave per dst node

    // layer 1: hA -> hB
    k_agg_h<<<aggb, 256, 0, stream>>>(hA, offs, ends, srcs, mean, 0, N);
    k_agg_h<<<aggb, 256, 0, stream>>>(hA, offs, ends, srcs, mean, 128, N);
    k_fgemm<<<mb, 512, 0, stream>>>(mean, Wlb[0], hA, Wrb[0], 2, bl[0], pa[0], hB, 1, N);
    // layer 2: hB -> hA
    k_agg_h<<<aggb, 256, 0, stream>>>(hB, offs, ends, srcs, mean, 0, N);
    k_agg_h<<<aggb, 256, 0, stream>>>(hB, offs, ends, srcs, mean, 128, N);
    k_fgemm<<<mb, 512, 0, stream>>>(mean, Wlb[1], hB, Wrb[1], 2, bl[1], pa[1], hA, 1, N);
    // layer 3: hA -> hB
    k_agg_h<<<aggb, 256, 0, stream>>>(hA, offs, ends, srcs, mean, 0, N);
    k_agg_h<<<aggb, 256, 0, stream>>>(hA, offs, ends, srcs, mean, 128, N);
    k_fgemm<<<mb, 512, 0, stream>>>(mean, Wlb[2], hA, Wrb[2], 2, bl[2], pa[2], hB, 1, N);
    // output projection -> fp32 d_out
    k_fgemm<<<mb, 512, 0, stream>>>(hB, Woutb, hB, Woutb, 1, bout, nullptr, d_out, 0, N);
}

// Round 5
// 1144.311 us; speedup vs baseline: 1.1976x; 1.1976x over previous
//
#include <hip/hip_runtime.h>

#define D 256
typedef unsigned short u16;
using short8  = __attribute__((ext_vector_type(8))) short;
using ushort8 = __attribute__((ext_vector_type(8))) unsigned short;
using f32x4   = __attribute__((ext_vector_type(4))) float;

#define BCHUNK  4096     // edges per binning block
#define FBINCAP 17500    // per fine-bin capacity (avg 16384, ~8.7 sigma margin)

__device__ __forceinline__ u16 f2bf(float f) {
    unsigned u = __float_as_uint(f);
    unsigned r = (u + 0x7FFFu + ((u >> 16) & 1u)) >> 16;
    return (u16)r;
}
__device__ __forceinline__ float bf2f(u16 v) {
    return __uint_as_float(((unsigned)v) << 16);
}

__device__ __forceinline__ void load_lds16(const u16* g, u16* l) {
    __builtin_amdgcn_global_load_lds(
        (const __attribute__((address_space(1))) void*)g,
        (__attribute__((address_space(3))) void*)l, 16, 0, 0);
}

// ---------------- CSR build ----------------

__global__ void k_initcur(int* __restrict__ bincur, int nfbin) {
    int i = threadIdx.x;
    if (i < nfbin) bincur[i] = i * FBINCAP;
}

__global__ __launch_bounds__(256)
void k_binf(const int* __restrict__ src, const int* __restrict__ dst,
            int* __restrict__ bincur, unsigned* __restrict__ bins,
            int E, int nfbin) {
    __shared__ int cnt[256];
    __shared__ int bpos[256];
    int t = threadIdx.x;
    int base = blockIdx.x * BCHUNK;
    cnt[t] = 0;
    __syncthreads();
    int lim = E - base; if (lim > BCHUNK) lim = BCHUNK;
    for (int i = t; i < lim; i += 256)
        atomicAdd(&cnt[dst[base + i] >> 9], 1);
    __syncthreads();
    if (t < nfbin) {
        int c = cnt[t];
        bpos[t] = c > 0 ? atomicAdd(&bincur[t], c) : 0;
    }
    __syncthreads();
    cnt[t] = 0;
    __syncthreads();
    for (int i = t; i < lim; i += 256) {
        int d = dst[base + i], s = src[base + i];
        int fb = d >> 9;
        int r = atomicAdd(&cnt[fb], 1);
        bins[(size_t)bpos[fb] + r] = (unsigned)s | ((unsigned)(d & 511) << 17);
    }
}

// One block per fine bin: LDS hist(512) -> scan -> placement -> coalesced
// srcs write. (R4's per-dst insertion sort REVERTED: cost +225us in csrf,
// bought only ~35us of agg locality.)
__global__ __launch_bounds__(256)
void k_csrf(const unsigned* __restrict__ bins, const int* __restrict__ bincur,
            int* __restrict__ offs, int* __restrict__ ends,
            int* __restrict__ srcs, int N) {
    __shared__ int cnt[512];
    __shared__ int cur[512];
    __shared__ int ssum[256];
    __shared__ int loc[FBINCAP];
    int b = blockIdx.x, t = threadIdx.x;
    int bbase = b * FBINCAP;
    int ecnt = bincur[b] - bbase;
    cnt[t] = 0; cnt[t + 256] = 0;
    __syncthreads();
    const unsigned* bp = bins + bbase;
    for (int i = t; i < ecnt; i += 256)
        atomicAdd(&cnt[bp[i] >> 17], 1);
    __syncthreads();
    int a0 = cnt[2 * t], a1 = cnt[2 * t + 1];
    ssum[t] = a0 + a1;
    __syncthreads();
    for (int o = 1; o < 256; o <<= 1) {
        int x = (t >= o) ? ssum[t - o] : 0;
        __syncthreads();
        ssum[t] += x;
        __syncthreads();
    }
    int excl = ssum[t] - (a0 + a1);
    cur[2 * t] = excl;
    cur[2 * t + 1] = excl + a0;
    int nbase = b << 9;
    int l0 = nbase + 2 * t, l1 = l0 + 1;
    if (l0 < N) { offs[l0] = bbase + excl;      ends[l0] = bbase + excl + a0; }
    if (l1 < N) { offs[l1] = bbase + excl + a0; ends[l1] = bbase + excl + a0 + a1; }
    __syncthreads();
    for (int i = t; i < ecnt; i += 256) {
        unsigned v = bp[i];
        int p = atomicAdd(&cur[v >> 17], 1);
        loc[p] = (int)(v & 0x1FFFFu);
    }
    __syncthreads();
    for (int i = t; i < ecnt; i += 256)
        srcs[bbase + i] = loc[i];
}

// ---------------- embedding gather -> bf16 ----------------

__global__ void k_gather_bf(const int* __restrict__ x, const float* __restrict__ emb,
                            u16* __restrict__ h, int N) {
    int idx = blockIdx.x * blockDim.x + threadIdx.x;
    if (idx >= N * 64) return;
    int node = idx >> 6, c = idx & 63;
    int s = x[node];
    float4 v = ((const float4*)emb)[(size_t)s * 64 + c];
    ushort4 o;
    o.x = f2bf(v.x); o.y = f2bf(v.y); o.z = f2bf(v.z); o.w = f2bf(v.w);
    ((ushort4*)h)[(size_t)node * 64 + c] = o;
}

// ---------------- weight fp32 -> bf16 ----------------

__global__ void k_cvtw(const float* w0, const float* w1, const float* w2,
                       const float* w3, const float* w4, const float* w5,
                       const float* w6, u16* __restrict__ out) {
    int idx = blockIdx.x * blockDim.x + threadIdx.x;
    if (idx >= 7 * 65536) return;
    int m = idx >> 16, off = idx & 65535;
    const float* w = w0;
    if (m == 1) w = w1; else if (m == 2) w = w2; else if (m == 3) w = w3;
    else if (m == 4) w = w4; else if (m == 5) w = w5; else if (m == 6) w = w6;
    out[idx] = f2bf(w[off]);
}

// ---------------- mean aggregation, both 128-col halves in ONE dispatch ----------------
// 256B/edge/pass = proven fetch-granule optimum. Grid = 2*aggb, x-major:
// all half-0 blocks (colOff=0) dispatch before half-1 -> co-resident window
// (~1500 blocks) stays within one half, preserving the 25.6MB per-pass WS.
// Merged so each layer's agg is ONE dispatch -> frees top-5 slots for
// GEMM/CSR visibility in rocprof.

__global__ __launch_bounds__(256)
void k_agg_h(const u16* __restrict__ h, const int* __restrict__ offs,
             const int* __restrict__ ends, const int* __restrict__ srcs,
             u16* __restrict__ out, int aggb, int N) {
    int xb = blockIdx.x;
    int colOff = 0;
    if (xb >= aggb) { colOff = 128; xb -= aggb; }
    int wid = (xb * 256 + threadIdx.x) >> 6;
    int lane = threadIdx.x & 63;
    if (wid >= N) return;
    int beg = offs[wid], end = ends[wid];
    int q = lane >> 4;             // edge slot 0..3
    int cl = lane & 15;            // 16B chunk within the 256B half-row
    const u16* hb = h + colOff + cl * 8;
    float acc[8];
    #pragma unroll
    for (int i = 0; i < 8; i++) acc[i] = 0.f;
    int e = beg + q;
    for (; e + 12 < end; e += 16) {
        int j0 = srcs[e], j1 = srcs[e + 4], j2 = srcs[e + 8], j3 = srcs[e + 12];
        ushort8 v0 = *(const ushort8*)&hb[(size_t)j0 * D];
        ushort8 v1 = *(const ushort8*)&hb[(size_t)j1 * D];
        ushort8 v2 = *(const ushort8*)&hb[(size_t)j2 * D];
        ushort8 v3 = *(const ushort8*)&hb[(size_t)j3 * D];
        #pragma unroll
        for (int i = 0; i < 8; i++)
            acc[i] += (bf2f(v0[i]) + bf2f(v1[i])) + (bf2f(v2[i]) + bf2f(v3[i]));
    }
    for (; e < end; e += 4) {
        int j = srcs[e];
        ushort8 v = *(const ushort8*)&hb[(size_t)j * D];
        #pragma unroll
        for (int i = 0; i < 8; i++) acc[i] += bf2f(v[i]);
    }
    #pragma unroll
    for (int i = 0; i < 8; i++) {
        acc[i] += __shfl_xor(acc[i], 16);
        acc[i] += __shfl_xor(acc[i], 32);
    }
    if (q == 0) {
        int dg = end - beg;
        float inv = 1.0f / (float)(dg < 1 ? 1 : dg);
        ushort8 o;
        #pragma unroll
        for (int i = 0; i < 8; i++) o[i] = f2bf(acc[i] * inv);
        *(ushort8*)&out[(size_t)wid * D + colOff + cl * 8] = o;
    }
}

// ---------------- fused MFMA GEMM: triple-buffer BK=32, counted vmcnt ----------------
// (unchanged from R3 — best-known GEMM; this round's merged-agg launch
// frees top-5 slots so its counters finally become visible)

__global__ __launch_bounds__(512, 4)
void k_fgemm(const u16* __restrict__ A0, const u16* __restrict__ W0,
             const u16* __restrict__ A1, const u16* __restrict__ W1,
             int npairs,
             const float* __restrict__ bias, const float* __restrict__ prelu_a,
             void* __restrict__ outp, int out_bf16, int M) {
    __shared__ u16 As[3][128 * 32];   // 8KB each
    __shared__ u16 Bs[3][256 * 32];   // 16KB each
    int t = threadIdx.x;
    int wave = t >> 6, lane = t & 63;
    int r = lane & 15, quad = lane >> 4;
    int wm = (wave & 1) * 64;
    int wn = (wave >> 1) * 64;
    int m0 = blockIdx.x * 128;

    f32x4 acc[4][4];
    #pragma unroll
    for (int i = 0; i < 4; i++)
        #pragma unroll
        for (int j = 0; j < 4; j++)
            acc[i][j] = (f32x4){0.f, 0.f, 0.f, 0.f};

    // staging: per wave-load, 64 lanes x 16B = 16 rows x 64B (4 chunks/row).
    int arow = wave * 16 + (lane >> 2);          // A row for this lane's 16B
    int scol = (((lane & 3) ^ ((lane >> 3) & 3)) << 3);  // pre-swizzled src col (u16)
    int nkt = npairs * 8;                        // K-steps of 32

    auto STAGE = [&](int buf, int kt) {
        const u16* Ag = (kt >= 8) ? A1 : A0;
        const u16* Wg = (kt >= 8) ? W1 : W0;
        int k0 = (kt & 7) * 32;
        load_lds16(Ag + (size_t)(m0 + arow) * D + k0 + scol,
                   &As[buf][wave * 512]);
        #pragma unroll
        for (int l = 0; l < 2; l++)
            load_lds16(Wg + (size_t)(l * 128 + arow) * D + k0 + scol,
                       &Bs[buf][l * 4096 + wave * 512]);
    };

    STAGE(0, 0);
    if (nkt > 1) STAGE(1, 1);

    int pch = quad ^ ((r >> 1) & 3);   // swizzled chunk for fragment reads
    int b0 = 0, b2 = 2;                // buf of step kt, buf to stage (kt+2)
    for (int kt = 0; kt < nkt; ++kt) {
        if (kt + 1 < nkt) asm volatile("s_waitcnt vmcnt(3)" ::: "memory");
        else              asm volatile("s_waitcnt vmcnt(0)" ::: "memory");
        __builtin_amdgcn_s_barrier();
        asm volatile("" ::: "memory");

        if (kt + 2 < nkt) STAGE(b2, kt + 2);

        short8 a[4], b[4];
        #pragma unroll
        for (int mt = 0; mt < 4; mt++)
            a[mt] = *(const short8*)&As[b0][(wm + mt * 16 + r) * 32 + pch * 8];
        #pragma unroll
        for (int nt = 0; nt < 4; nt++)
            b[nt] = *(const short8*)&Bs[b0][(wn + nt * 16 + r) * 32 + pch * 8];

        __builtin_amdgcn_s_setprio(1);
        #pragma unroll
        for (int mt = 0; mt < 4; mt++)
            #pragma unroll
            for (int nt = 0; nt < 4; nt++)
                acc[mt][nt] = __builtin_amdgcn_mfma_f32_16x16x32_bf16(
                    a[mt], b[nt], acc[mt][nt], 0, 0, 0);
        __builtin_amdgcn_s_setprio(0);

        b0 = (b0 == 2) ? 0 : b0 + 1;
        b2 = (b2 == 2) ? 0 : b2 + 1;
    }

    float pa = prelu_a ? *prelu_a : 0.f;
    int dop = prelu_a != nullptr;
    #pragma unroll
    for (int nt = 0; nt < 4; nt++) {
        int col = wn + nt * 16 + r;
        float bv = bias ? bias[col] : 0.f;
        #pragma unroll
        for (int mt = 0; mt < 4; mt++) {
            #pragma unroll
            for (int i = 0; i < 4; i++) {
                int row = m0 + wm + mt * 16 + quad * 4 + i;
                if (row < M) {
                    float v = acc[mt][nt][i] + bv;
                    if (dop) v = (v >= 0.f) ? v : pa * v;
                    if (out_bf16)
                        ((u16*)outp)[(size_t)row * D + col] = f2bf(v);
                    else
                        ((float*)outp)[(size_t)row * D + col] = v;
                }
            }
        }
    }
}

// ---------------- launcher ----------------

extern "C" void kernel_launch(void* const* d_in, const int* in_sizes, int n_in,
                              void* d_out, int out_size, void* d_ws, size_t ws_size,
                              hipStream_t stream) {
    const int*   x    = (const int*)d_in[0];
    const int*   ei   = (const int*)d_in[1];
    const float* emb  = (const float*)d_in[3];
    const float* Wl[3] = {(const float*)d_in[4],  (const float*)d_in[8],  (const float*)d_in[12]};
    const float* bl[3] = {(const float*)d_in[5],  (const float*)d_in[9],  (const float*)d_in[13]};
    const float* Wr[3] = {(const float*)d_in[6],  (const float*)d_in[10], (const float*)d_in[14]};
    const float* pa[3] = {(const float*)d_in[7],  (const float*)d_in[11], (const float*)d_in[15]};
    const float* Wout = (const float*)d_in[16];
    const float* bout = (const float*)d_in[17];

    int N = in_sizes[0];
    int E = in_sizes[1] / 2;
    const int* src = ei;
    const int* dst = ei + E;
    int nfbin = (N + 511) >> 9;    // 196 for N=100000

    char* ws = (char*)d_ws;
    size_t off = 0;
    auto walloc = [&](size_t bytes) -> void* {
        void* p = ws + off;
        off += (bytes + 255) & ~(size_t)255;
        return p;
    };
    // tile staging over-reads up to ~49 KB past row M-1: keep activations mid-ws
    u16* hA   = (u16*)walloc((size_t)N * D * sizeof(u16));
    u16* hB   = (u16*)walloc((size_t)N * D * sizeof(u16));
    u16* mean = (u16*)walloc((size_t)N * D * sizeof(u16));
    u16* wbf  = (u16*)walloc((size_t)7 * 65536 * sizeof(u16));
    int* offs   = (int*)walloc((size_t)N * sizeof(int));
    int* ends   = (int*)walloc((size_t)N * sizeof(int));
    int* bincur = (int*)walloc(1024);
    unsigned* bins = (unsigned*)walloc((size_t)nfbin * FBINCAP * sizeof(unsigned));
    int* srcs   = (int*)walloc((size_t)nfbin * FBINCAP * sizeof(int));

    u16* Wlb[3] = {wbf + 0 * 65536, wbf + 2 * 65536, wbf + 4 * 65536};
    u16* Wrb[3] = {wbf + 1 * 65536, wbf + 3 * 65536, wbf + 5 * 65536};
    u16* Woutb  = wbf + 6 * 65536;

    // --- weights -> bf16 ---
    k_cvtw<<<(7 * 65536 + 255) / 256, 256, 0, stream>>>(
        Wl[0], Wr[0], Wl[1], Wr[1], Wl[2], Wr[2], Wout, wbf);

    // --- CSR build: fine-bin + in-LDS sort ---
    k_initcur<<<1, 256, 0, stream>>>(bincur, nfbin);
    int bb = (E + BCHUNK - 1) / BCHUNK;
    k_binf<<<bb, 256, 0, stream>>>(src, dst, bincur, bins, E, nfbin);
    k_csrf<<<nfbin, 256, 0, stream>>>(bins, bincur, offs, ends, srcs, N);

    // --- h0 = bf16(emb[x]) ---
    k_gather_bf<<<(N * 64 + 255) / 256, 256, 0, stream>>>(x, emb, hA, N);

    int mb   = (N + 127) / 128;
    int aggb = (N * 64 + 255) / 256;   // blocks per half (one wave per node)

    // layer 1: hA -> hB
    k_agg_h<<<2 * aggb, 256, 0, stream>>>(hA, offs, ends, srcs, mean, aggb, N);
    k_fgemm<<<mb, 512, 0, stream>>>(mean, Wlb[0], hA, Wrb[0], 2, bl[0], pa[0], hB, 1, N);
    // layer 2: hB -> hA
    k_agg_h<<<2 * aggb, 256, 0, stream>>>(hB, offs, ends, srcs, mean, aggb, N);
    k_fgemm<<<mb, 512, 0, stream>>>(mean, Wlb[1], hB, Wrb[1], 2, bl[1], pa[1], hA, 1, N);
    // layer 3: hA -> hB
    k_agg_h<<<2 * aggb, 256, 0, stream>>>(hA, offs, ends, srcs, mean, aggb, N);
    k_fgemm<<<mb, 512, 0, stream>>>(mean, Wlb[2], hA, Wrb[2], 2, bl[2], pa[2], hB, 1, N);
    // output projection -> fp32 d_out
    k_fgemm<<<mb, 512, 0, stream>>>(hB, Woutb, hB, Woutb, 1, bout, nullptr, d_out, 0, N);
}